// Round 1
// baseline (1050.982 us; speedup 1.0000x reference)
//
#include <hip/hip_runtime.h>

// LSS view transformer: softmax over depth, outer-product with features,
// scatter-sum into BEV grid. Index map is input-independent (rots/trans/
// intrins are dead in the reference), shared across cameras.

constexpr int D = 40, H = 32, W = 88, HW = H * W;       // 2816
constexpr int C = 128, NCAM = 6;
constexpr int BEV = 125, NBINS = BEV * BEV;             // 15625

// ---------------------------------------------------------------- softmax
// One thread per (n, h, w) column; strided over D. Coalesced in w.
__global__ void softmax_kernel(const float* __restrict__ logits,
                               float* __restrict__ probs) {
    int tid = blockIdx.x * blockDim.x + threadIdx.x;
    if (tid >= NCAM * HW) return;
    int n  = tid / HW;
    int hw = tid - n * HW;
    const float* src = logits + (size_t)n * D * HW + hw;
    float*       dst = probs  + (size_t)n * D * HW + hw;

    float v[D];
    float m = -3.402823466e+38f;
#pragma unroll
    for (int d = 0; d < D; ++d) {
        v[d] = src[(size_t)d * HW];
        m = fmaxf(m, v[d]);
    }
    float s = 0.f;
#pragma unroll
    for (int d = 0; d < D; ++d) {
        v[d] = expf(v[d] - m);
        s += v[d];
    }
    float inv = 1.0f / s;
#pragma unroll
    for (int d = 0; d < D; ++d)
        dst[(size_t)d * HW] = v[d] * inv;
}

// ---------------------------------------------------------------- bin table
// Exact IEEE fp32 replication of _voxel_indices() (no FMA contraction:
// __f*_rn intrinsics). max1 = 87*41 = 3567, max2 = 31*41 = 1271 (exact).
// iz = (dep+10)/20 >= 0 always (dep >= 2), so it never invalidates.
__global__ void idx_kernel(int* __restrict__ tab) {
    int tid = blockIdx.x * blockDim.x + threadIdx.x;
    if (tid >= D * HW) return;
    int d  = tid / HW;
    int hw = tid - d * HW;
    int h  = hw / W;
    int w  = hw - h * W;

    float dep = (float)(d + 2);
    float xd  = (float)w * dep;                 // exact ints < 2^24
    float yd  = (float)h * dep;

    float gx = __fadd_rn(__fmul_rn(__fdiv_rn(xd, 3567.0f), 100.0f), -50.0f);
    float gy = __fadd_rn(__fmul_rn(__fdiv_rn(yd, 1271.0f), 100.0f), -50.0f);
    int ix = (int)__fdiv_rn(__fadd_rn(gx, 50.0f), 0.8f);   // (gx - X_MIN)/DX
    int iy = (int)__fdiv_rn(__fadd_rn(gy, 50.0f), 0.8f);

    bool valid = (ix >= 0) & (ix < BEV) & (iy >= 0) & (iy < BEV);
    tab[tid] = valid ? (iy * BEV + ix) : -1;
}

// ---------------------------------------------------------------- scatter
// One block per (h,w); thread = channel c. Camera features held in
// registers (loaded once, reused for all 40 depths). Per depth: reduce over
// cameras in registers, then ONE atomicAdd per (d,hw,c). Lanes within a
// wave hit distinct addresses (distinct c) -> no intra-wave same-address
// serialization. 2816*40*128 = 14.4M atomics total.
__global__ void __launch_bounds__(C) scatter_kernel(
        const float* __restrict__ feat,    // [NCAM][C][HW]
        const float* __restrict__ probs,   // [NCAM][D][HW]
        const int*   __restrict__ tab,     // [D][HW]
        float*       __restrict__ out) {   // [C][NBINS]
    int hw = blockIdx.x;
    int c  = threadIdx.x;

    float f[NCAM];
#pragma unroll
    for (int n = 0; n < NCAM; ++n)
        f[n] = feat[((size_t)(n * C + c)) * HW + hw];

    float* outc = out + (size_t)c * NBINS;

    for (int d = 0; d < D; ++d) {
        int bin = tab[d * HW + hw];        // wave-uniform, L1 broadcast
        if (bin >= 0) {
            float s = 0.f;
#pragma unroll
            for (int n = 0; n < NCAM; ++n)
                s += probs[((size_t)n * D + d) * HW + hw] * f[n];
            atomicAdd(&outc[bin], s);
        }
    }
}

// ---------------------------------------------------------------- launch
extern "C" void kernel_launch(void* const* d_in, const int* in_sizes, int n_in,
                              void* d_out, int out_size, void* d_ws, size_t ws_size,
                              hipStream_t stream) {
    const float* img_feat     = (const float*)d_in[0];  // (1,6,128,32,88)
    const float* depth_logits = (const float*)d_in[1];  // (1,6,40,32,88)
    // d_in[2..4] (rots/trans/intrins) are dead in the reference.

    float* probs = (float*)d_ws;                               // 6*40*2816 f32 = 10.8 MB
    int*   tab   = (int*)((char*)d_ws +
                          (size_t)NCAM * D * HW * sizeof(float)); // 40*2816 i32 = 450 KB
    float* out   = (float*)d_out;                              // (1,128,125,125)

    hipMemsetAsync(d_out, 0, (size_t)out_size * sizeof(float), stream);

    softmax_kernel<<<(NCAM * HW + 255) / 256, 256, 0, stream>>>(depth_logits, probs);
    idx_kernel<<<(D * HW + 255) / 256, 256, 0, stream>>>(tab);
    scatter_kernel<<<HW, C, 0, stream>>>(img_feat, probs, tab, out);
}

// Round 2
// 213.092 us; speedup vs baseline: 4.9320x; 4.9320x over previous
//
#include <hip/hip_runtime.h>

// LSS view transformer, gather formulation.
// R0 post-mortem: 986us scatter was atomic-bound (450MB WRITE_SIZE for 8MB out,
// VALUBusy 0.27%). The bin map is input-independent -> build CSR (bin -> list of
// (d,hw)) on device each launch, then one block per bin gathers with zero output
// atomics and writes each out element exactly once.

constexpr int D = 40, H = 32, W = 88, HW = H * W;       // 2816
constexpr int C = 128, NCAM = 6;
constexpr int BEV = 125, NBINS = BEV * BEV;             // 15625
constexpr int NPTS = D * HW;                            // 112640

// ---------------------------------------------------------------- softmax
__global__ void softmax_kernel(const float* __restrict__ logits,
                               float* __restrict__ probs) {
    int tid = blockIdx.x * blockDim.x + threadIdx.x;
    if (tid >= NCAM * HW) return;
    int n  = tid / HW;
    int hw = tid - n * HW;
    const float* src = logits + (size_t)n * D * HW + hw;
    float*       dst = probs  + (size_t)n * D * HW + hw;

    float v[D];
    float m = -3.402823466e+38f;
#pragma unroll
    for (int d = 0; d < D; ++d) {
        v[d] = src[(size_t)d * HW];
        m = fmaxf(m, v[d]);
    }
    float s = 0.f;
#pragma unroll
    for (int d = 0; d < D; ++d) {
        v[d] = expf(v[d] - m);
        s += v[d];
    }
    float inv = 1.0f / s;
#pragma unroll
    for (int d = 0; d < D; ++d)
        dst[(size_t)d * HW] = v[d] * inv;
}

// ---------------------------------------------------------------- feat transpose
// feat[n][c][hw] -> feat_t[hw][n][c]  (so gather reads are coalesced in c)
__global__ void __launch_bounds__(256) transpose_kernel(
        const float* __restrict__ feat, float* __restrict__ feat_t) {
    __shared__ float tile[32][33];
    int n   = blockIdx.z;
    int c0  = blockIdx.y * 32;
    int hw0 = blockIdx.x * 32;
    int x = threadIdx.x;            // 0..31
    int y = threadIdx.y;            // 0..7
#pragma unroll
    for (int i = 0; i < 32; i += 8) {
        tile[y + i][x] = feat[((size_t)(n * C + c0 + y + i)) * HW + hw0 + x];
    }
    __syncthreads();
#pragma unroll
    for (int i = 0; i < 32; i += 8) {
        int hw = hw0 + y + i;
        int c  = c0 + x;
        feat_t[((size_t)hw * NCAM + n) * C + c] = tile[x][y + i];
    }
}

// ---------------------------------------------------------------- bin table + histogram
// Exact IEEE fp32 replication of _voxel_indices() (no FMA contraction).
__global__ void idx_hist_kernel(int* __restrict__ tab, int* __restrict__ cnt) {
    int tid = blockIdx.x * blockDim.x + threadIdx.x;
    if (tid >= NPTS) return;
    int d  = tid / HW;
    int hw = tid - d * HW;
    int h  = hw / W;
    int w  = hw - h * W;

    float dep = (float)(d + 2);
    float xd  = (float)w * dep;
    float yd  = (float)h * dep;

    float gx = __fadd_rn(__fmul_rn(__fdiv_rn(xd, 3567.0f), 100.0f), -50.0f);
    float gy = __fadd_rn(__fmul_rn(__fdiv_rn(yd, 1271.0f), 100.0f), -50.0f);
    int ix = (int)__fdiv_rn(__fadd_rn(gx, 50.0f), 0.8f);
    int iy = (int)__fdiv_rn(__fadd_rn(gy, 50.0f), 0.8f);

    bool valid = (ix >= 0) & (ix < BEV) & (iy >= 0) & (iy < BEV);
    int bin = valid ? (iy * BEV + ix) : -1;
    tab[tid] = bin;
    if (bin >= 0) atomicAdd(&cnt[bin], 1);
}

// ---------------------------------------------------------------- exclusive scan
// Single block, 1024 threads x 16 bins each (16384 >= 15625).
__global__ void __launch_bounds__(1024) scan_kernel(
        const int* __restrict__ cnt, int* __restrict__ offsets) {
    __shared__ int part[1024];
    int t = threadIdx.x;
    int base = t * 16;
    int local[16];
    int s = 0;
#pragma unroll
    for (int i = 0; i < 16; ++i) {
        int idx = base + i;
        int v = (idx < NBINS) ? cnt[idx] : 0;
        local[i] = s;
        s += v;
    }
    part[t] = s;
    __syncthreads();
    for (int off = 1; off < 1024; off <<= 1) {
        int v = (t >= off) ? part[t - off] : 0;
        __syncthreads();
        part[t] += v;
        __syncthreads();
    }
    int pre = (t == 0) ? 0 : part[t - 1];
#pragma unroll
    for (int i = 0; i < 16; ++i) {
        int idx = base + i;
        if (idx < NBINS) offsets[idx] = pre + local[i];
    }
    if (t == 1023) offsets[NBINS] = part[1023];
}

// ---------------------------------------------------------------- CSR fill
__global__ void fill_kernel(const int* __restrict__ tab,
                            const int* __restrict__ offsets,
                            int* __restrict__ cursor,
                            int* __restrict__ entries) {
    int tid = blockIdx.x * blockDim.x + threadIdx.x;
    if (tid >= NPTS) return;
    int bin = tab[tid];
    if (bin < 0) return;
    int d  = tid / HW;
    int hw = tid - d * HW;
    int pos = atomicAdd(&cursor[bin], 1);
    entries[offsets[bin] + pos] = (d << 12) | hw;   // hw < 4096
}

// ---------------------------------------------------------------- gather
// One block per bin. 256 threads = 2 entry-groups x 128 channels.
// feat_t reads coalesced in c; probs reads wave-uniform (broadcast).
// Every output element written exactly once -> no atomics, no out memset.
__global__ void __launch_bounds__(256) gather_kernel(
        const float* __restrict__ feat_t,   // [HW][NCAM][C]
        const float* __restrict__ probs,    // [NCAM][D][HW]
        const int*   __restrict__ entries,
        const int*   __restrict__ offsets,
        float*       __restrict__ out) {    // [C][NBINS]
    int bin = blockIdx.x;
    int c = threadIdx.x & 127;
    int g = threadIdx.x >> 7;               // 0 or 1
    int beg = offsets[bin], end = offsets[bin + 1];

    float acc = 0.f;
    for (int e = beg + g; e < end; e += 2) {
        int pk = entries[e];
        int hw = pk & 4095;
        int d  = pk >> 12;
        const float* fp = feat_t + (size_t)hw * (NCAM * C) + c;
        const float* pp = probs + (size_t)d * HW + hw;
        float s = 0.f;
#pragma unroll
        for (int n = 0; n < NCAM; ++n)
            s += pp[(size_t)n * D * HW] * fp[n * C];
        acc += s;
    }

    __shared__ float red[128];
    if (g == 1) red[c] = acc;
    __syncthreads();
    if (g == 0) out[(size_t)c * NBINS + bin] = acc + red[c];
}

// ---------------------------------------------------------------- launch
extern "C" void kernel_launch(void* const* d_in, const int* in_sizes, int n_in,
                              void* d_out, int out_size, void* d_ws, size_t ws_size,
                              hipStream_t stream) {
    const float* img_feat     = (const float*)d_in[0];  // (1,6,128,32,88)
    const float* depth_logits = (const float*)d_in[1];  // (1,6,40,32,88)
    float* out = (float*)d_out;                         // (1,128,125,125)

    // workspace layout (bytes)
    char* p = (char*)d_ws;
    float* probs   = (float*)p;                 p += (size_t)NCAM * D * HW * 4;   // 2.70 MB
    float* feat_t  = (float*)p;                 p += (size_t)HW * NCAM * C * 4;   // 8.65 MB
    int*   tab     = (int*)p;                   p += (size_t)NPTS * 4;            // 450 KB
    int*   entries = (int*)p;                   p += (size_t)NPTS * 4;            // 450 KB
    int*   offsets = (int*)p;                   p += (size_t)(NBINS + 1) * 4;
    int*   cnt     = (int*)p;                   p += (size_t)NBINS * 4;
    int*   cursor  = (int*)p;                   p += (size_t)NBINS * 4;

    // zero cnt + cursor (adjacent) — ws is poisoned before every launch
    hipMemsetAsync(cnt, 0, (size_t)NBINS * 2 * 4, stream);

    softmax_kernel<<<(NCAM * HW + 255) / 256, 256, 0, stream>>>(depth_logits, probs);
    transpose_kernel<<<dim3(HW / 32, C / 32, NCAM), dim3(32, 8), 0, stream>>>(img_feat, feat_t);
    idx_hist_kernel<<<(NPTS + 255) / 256, 256, 0, stream>>>(tab, cnt);
    scan_kernel<<<1, 1024, 0, stream>>>(cnt, offsets);
    fill_kernel<<<(NPTS + 255) / 256, 256, 0, stream>>>(tab, offsets, cursor, entries);
    gather_kernel<<<NBINS, 256, 0, stream>>>(feat_t, probs, entries, offsets, out);
}